// Round 10
// baseline (939.095 us; speedup 1.0000x reference)
//
#include <hip/hip_runtime.h>
#include <hip/hip_bf16.h>
#include <math.h>

// MimiAttention: B=4, S=2048, HID=512, NH=8, HD=64, SW=250, theta=10000
// Round 21: MEGAFUSION. Accounting across r11/r13/r16 totals shows the
// remaining budget is ~45us harness ws-poison fill + ~27us inter-dispatch
// gaps + kernels {cvt 5.5, qkv 25, attn 18.6, out 5}. Gaps are now the
// largest controllable item -> fuse all 4 kernels into ONE 1024-block
// launch with 3 software global barriers (device-scope atomics + agent
// fences). Residency GUARANTEED: __launch_bounds__(256,4) caps VGPR=128,
// LDS = one 34816B union -> 4 blocks/CU by both limits -> 1024 co-resident,
// no deadlock; bounded spin turns surprises into clean fails.
// Counters at ws+48MB, zeroed by hipMemsetAsync (capturable).
// Phase bodies = r20-verified code (125.6us baseline).

#define B_   4
#define S_   2048
#define HID_ 512
#define NH_  8
#define HD_  64
#define SW_  250

typedef __bf16 bf16x8 __attribute__((ext_vector_type(8)));
typedef __bf16 bf16x4 __attribute__((ext_vector_type(4)));
typedef float f32x4 __attribute__((ext_vector_type(4)));
using bf16_t = __hip_bfloat16;
typedef unsigned int u32;

// async global->LDS, 16 B per lane (wave-uniform base + lane*16 semantics)
__device__ __forceinline__ void glds16(const void* g, void* l) {
    __builtin_amdgcn_global_load_lds(
        (const __attribute__((address_space(1))) u32*)g,
        (__attribute__((address_space(3))) u32*)l, 16, 0, 0);
}

// device-scope barrier across all 1024 co-resident blocks.
// release: syncthreads + agent fence (L2 wb) + atomicAdd; spin on counter;
// acquire: syncthreads + agent fence (L2/L1 inv) by every thread.
__device__ __forceinline__ void gbar(int* cnt) {
    __syncthreads();
    __threadfence();
    if (threadIdx.x == 0) {
        __hip_atomic_fetch_add(cnt, 1, __ATOMIC_RELEASE, __HIP_MEMORY_SCOPE_AGENT);
        int it = 0;
        while (__hip_atomic_load(cnt, __ATOMIC_ACQUIRE, __HIP_MEMORY_SCOPE_AGENT) < 1024) {
            __builtin_amdgcn_s_sleep(16);
            if (++it > (1 << 24)) break;   // safety: legit waits are us-scale
        }
    }
    __syncthreads();
    __threadfence();
}

// ---------------------------------------------------------------------------
__global__ __launch_bounds__(256, 4) void mega(
    const float* __restrict__ X,  const float* __restrict__ Wq,
    const float* __restrict__ Wk, const float* __restrict__ Wv,
    const float* __restrict__ Wo,
    bf16_t* __restrict__ Xb, bf16_t* __restrict__ Wcat, bf16_t* __restrict__ Wob,
    bf16_t* __restrict__ Q,  bf16_t* __restrict__ Kb,   bf16_t* __restrict__ Vt,
    bf16_t* __restrict__ A,  float* __restrict__ out,   int* __restrict__ bar)
{
    __shared__ __align__(16) char smem_raw[34816];
    bf16_t* const sm = (bf16_t*)smem_raw;
    const int bid = blockIdx.x;
    const int tid = threadIdx.x;
    const int wave = tid >> 6, lane = tid & 63;
    const int quad = lane >> 4, l16 = lane & 15;

    // ================= phase 0: fp32 -> bf16 convert (2560 units) ==========
    for (int u = bid; u < 2560; u += 1024) {
        const float* s; bf16_t* d; size_t base;
        if (u < 2048)      { s = X;  d = Xb;            base = (size_t)u * 2048; }
        else if (u < 2176) { s = Wq; d = Wcat;          base = (size_t)(u - 2048) * 2048; }
        else if (u < 2304) { s = Wk; d = Wcat + 262144; base = (size_t)(u - 2176) * 2048; }
        else if (u < 2432) { s = Wv; d = Wcat + 524288; base = (size_t)(u - 2304) * 2048; }
        else               { s = Wo; d = Wob;           base = (size_t)(u - 2432) * 2048; }
        size_t i = base + (size_t)tid * 8;
        float4 a = *reinterpret_cast<const float4*>(s + i);
        float4 b = *reinterpret_cast<const float4*>(s + i + 4);
        bf16x8 r;
        r[0] = (__bf16)a.x; r[1] = (__bf16)a.y; r[2] = (__bf16)a.z; r[3] = (__bf16)a.w;
        r[4] = (__bf16)b.x; r[5] = (__bf16)b.y; r[6] = (__bf16)b.z; r[7] = (__bf16)b.w;
        *reinterpret_cast<bf16x8*>(d + i) = r;
    }
    gbar(bar + 0);

    // ================= phase 1: QKV GEMM + RoPE (768 units) ================
    if (bid < 768) {
        const int wm = wave & 1, wn = wave >> 1;
        const int xcd = bid & 7, slot = bid >> 3;
        const int mi = xcd * 8 + (slot & 7);
        const int ni = slot >> 3;
        const int m0 = mi * 128, n0 = ni * 128;

        const int srow0 = tid >> 2,           sl0 = (tid & 3) ^ ((srow0 >> 1) & 3);
        const int srow1 = (256 + tid) >> 2,   sl1 = ((256 + tid) & 3) ^ ((srow1 >> 1) & 3);

        glds16(Xb   + (size_t)(m0 + srow0) * HID_ + sl0 * 8, sm + tid * 8);
        glds16(Wcat + (size_t)(n0 + srow0) * HID_ + sl0 * 8, sm + 4096 + tid * 8);
        glds16(Xb   + (size_t)(m0 + srow1) * HID_ + sl1 * 8, sm + (256 + tid) * 8);
        glds16(Wcat + (size_t)(n0 + srow1) * HID_ + sl1 * 8, sm + 4096 + (256 + tid) * 8);

        f32x4 acc[4][4] = {};
        for (int t = 0; t < 16; ++t) {
            const int curo = (t & 1) * 8192;
            if (t + 1 < 16) {
                const int nxto = curo ^ 8192;
                const int k1 = (t + 1) * 32;
                glds16(Xb   + (size_t)(m0 + srow0) * HID_ + k1 + sl0 * 8, sm + nxto + tid * 8);
                glds16(Wcat + (size_t)(n0 + srow0) * HID_ + k1 + sl0 * 8, sm + nxto + 4096 + tid * 8);
                glds16(Xb   + (size_t)(m0 + srow1) * HID_ + k1 + sl1 * 8, sm + nxto + (256 + tid) * 8);
                glds16(Wcat + (size_t)(n0 + srow1) * HID_ + k1 + sl1 * 8, sm + nxto + 4096 + (256 + tid) * 8);
                asm volatile("s_waitcnt vmcnt(4)" ::: "memory");
            } else {
                asm volatile("s_waitcnt vmcnt(0)" ::: "memory");
            }
            __builtin_amdgcn_sched_barrier(0);
            __builtin_amdgcn_s_barrier();
            __builtin_amdgcn_sched_barrier(0);

            bf16x8 af[4], bfr[4];
#pragma unroll
            for (int i = 0; i < 4; ++i) {
                int ra = wm * 64 + i * 16 + l16;
                int rb = wn * 64 + i * 16 + l16;
                int pa = quad ^ ((ra >> 1) & 3);
                int pb = quad ^ ((rb >> 1) & 3);
                af[i]  = *reinterpret_cast<const bf16x8*>(sm + curo + ra * 32 + pa * 8);
                bfr[i] = *reinterpret_cast<const bf16x8*>(sm + curo + 4096 + rb * 32 + pb * 8);
            }
#pragma unroll
            for (int mi2 = 0; mi2 < 4; ++mi2)
#pragma unroll
                for (int ni2 = 0; ni2 < 4; ++ni2)
                    acc[mi2][ni2] = __builtin_amdgcn_mfma_f32_16x16x32_bf16(af[mi2], bfr[ni2], acc[mi2][ni2], 0, 0, 0);
            asm volatile("" ::: "memory");
            __builtin_amdgcn_sched_barrier(0);
            __builtin_amdgcn_s_barrier();
            __builtin_amdgcn_sched_barrier(0);
        }

        const int seg = n0 >> 9;
        const int hh = ((n0 & 511) + wn * 64) >> 6;
        bf16_t* wt = sm + wave * 4352;
        const int mbase = m0 + wm * 64;
        const int bb = mbase >> 11;
        const int sbase = mbase & (S_ - 1);

        if (seg < 2) {
            const float qs = (seg == 0) ? 0.125f : 1.0f;
            const float c = 0.41524101186f;           // log2(10000)/32
            float inv0 = exp2f(-(float)l16 * c);
            float inv1 = exp2f(-(float)(l16 + 16) * c);
#pragma unroll
            for (int mi2 = 0; mi2 < 4; ++mi2)
#pragma unroll
                for (int r = 0; r < 4; ++r) {
                    int lrow = mi2 * 16 + quad * 4 + r;
                    float sf = (float)(sbase + lrow);
#pragma unroll
                    for (int ip = 0; ip < 2; ++ip) {
                        float sn, cs_;
                        __sincosf(sf * (ip ? inv1 : inv0), &sn, &cs_);
                        float x1 = acc[mi2][ip][r], x2 = acc[mi2][ip + 2][r];
                        wt[lrow * 68 + ip * 16 + l16]      = __float2bfloat16((x1 * cs_ - x2 * sn) * qs);
                        wt[lrow * 68 + ip * 16 + l16 + 32] = __float2bfloat16((x2 * cs_ + x1 * sn) * qs);
                    }
                }
            bf16_t* Y = (seg == 0) ? Q : Kb;
#pragma unroll
            for (int it = 0; it < 8; ++it) {
                int e = it * 64 + lane;
                int sr = e >> 3, doff = (e & 7) * 8;
                size_t g2 = ((size_t)(bb * NH_ + hh) * S_ + sbase + sr) * HD_ + doff;
                *reinterpret_cast<bf16x8*>(Y + g2) =
                    *reinterpret_cast<const bf16x8*>(wt + sr * 68 + doff);
            }
        } else {
#pragma unroll
            for (int mi2 = 0; mi2 < 4; ++mi2)
#pragma unroll
                for (int ni2 = 0; ni2 < 4; ++ni2)
#pragma unroll
                    for (int r = 0; r < 4; ++r)
                        wt[(ni2 * 16 + l16) * 68 + mi2 * 16 + quad * 4 + r] =
                            __float2bfloat16(acc[mi2][ni2][r]);
#pragma unroll
            for (int it = 0; it < 8; ++it) {
                int e = it * 64 + lane;
                int d = e >> 3, soff = (e & 7) * 8;
                size_t g2 = ((size_t)(bb * NH_ + hh) * HD_ + d) * S_ + sbase + soff;
                *reinterpret_cast<bf16x8*>(Vt + g2) =
                    *reinterpret_cast<const bf16x8*>(wt + d * 68 + soff);
            }
        }
    }
    gbar(bar + 1);

    // ================= phase 2: attention (1024 units) =====================
    {
        // LDS carve (bytes): Ks0 @0, Ks1 @4096, Vs0 @8192, Vs1 @12288,
        // pt @16384 (5120), sums @21504 (256)
        __bf16* Ksp = (__bf16*)smem_raw;
        __bf16* Vsp = (__bf16*)(smem_raw + 8192);
        __bf16* ptp = (__bf16*)(smem_raw + 16384);
        float* sums_l = (float*)(smem_raw + 21504);

        const int xcd = bid & 7, slot = bid >> 3;
        const int bh = xcd * 4 + (slot >> 5);
        const int qt = slot & 31;
        const int b = bh >> 3, h = bh & 7;
        const int q0b = qt * 64;
        const int q0 = q0b + wave * 16;

        const size_t bh_ = (size_t)(b * NH_ + h) * S_;
        const size_t bhd = (size_t)(b * NH_ + h) * HD_;

        bf16x8 qf0, qf1;
        {
            const bf16_t* qp = Q + (bh_ + q0 + l16) * HD_ + quad * 8;
            qf0 = *reinterpret_cast<const bf16x8*>(qp);
            qf1 = *reinterpret_cast<const bf16x8*>(qp + 32);
        }
        const int kstartB = (q0b > SW_) ? ((q0b - SW_) & ~31) : 0;
        const int ntB = (q0b + 95 - kstartB) >> 5;     // 2..12, block-uniform
        const int qq = q0 + l16;

        const int krow = tid >> 3, kl = (tid & 7) ^ (krow & 7);
        const int vrow = tid >> 2, vl = (tid & 3) ^ (vrow & 3);

        {
            const int kb = kstartB;
            glds16(Kb + (bh_ + kb + krow) * HD_ + kl * 8, &Ksp[tid * 8]);
            glds16(Vt + (bhd + vrow) * S_ + kb + vl * 8, &Vsp[tid * 8]);
        }

        float sum = 0.f;
        f32x4 o[4] = {};
        for (int t = 0; t < ntB; ++t) {
            const int cur = t & 1;
            const int kb = kstartB + t * 32;
            if (t + 1 < ntB) {
                const int kb2 = kb + 32;
                glds16(Kb + (bh_ + kb2 + krow) * HD_ + kl * 8, &Ksp[(cur ^ 1) * 2048 + tid * 8]);
                glds16(Vt + (bhd + vrow) * S_ + kb2 + vl * 8, &Vsp[(cur ^ 1) * 2048 + tid * 8]);
                asm volatile("s_waitcnt vmcnt(2)" ::: "memory");
            } else {
                asm volatile("s_waitcnt vmcnt(0)" ::: "memory");
            }
            __builtin_amdgcn_s_barrier();
            asm volatile("" ::: "memory");

#pragma unroll
            for (int half = 0; half < 2; ++half) {
                const int rowt = half * 16 + l16;
                const int p0 = quad ^ (rowt & 7);
                const int p1 = (quad ^ 4) ^ (rowt & 7);
                bf16x8 k0 = *reinterpret_cast<const bf16x8*>(&Ksp[cur * 2048 + rowt * 64 + p0 * 8]);
                bf16x8 k1 = *reinterpret_cast<const bf16x8*>(&Ksp[cur * 2048 + rowt * 64 + p1 * 8]);
                f32x4 z = {};
                z = __builtin_amdgcn_mfma_f32_16x16x32_bf16(k0, qf0, z, 0, 0, 0);
                z = __builtin_amdgcn_mfma_f32_16x16x32_bf16(k1, qf1, z, 0, 0, 0);
                const int kbase = kb + half * 16 + quad * 4;
                bf16x4 pk;
#pragma unroll
                for (int r = 0; r < 4; ++r) {
                    int key = kbase + r;
                    bool keep = (key <= qq) && (qq - key <= SW_);
                    float p = keep ? __expf(z[r]) : 0.f;
                    sum += p;
                    pk[r] = (__bf16)p;
                }
                *reinterpret_cast<bf16x4*>(&ptp[wave * 640 + l16 * 40 + half * 16 + quad * 4]) = pk;
            }
            bf16x8 pf = *reinterpret_cast<const bf16x8*>(&ptp[wave * 640 + l16 * 40 + quad * 8]);
#pragma unroll
            for (int nf = 0; nf < 4; ++nf) {
                const int rowv = nf * 16 + l16;
                const int pv = quad ^ (rowv & 3);
                bf16x8 vf = *reinterpret_cast<const bf16x8*>(&Vsp[cur * 2048 + rowv * 32 + pv * 8]);
                o[nf] = __builtin_amdgcn_mfma_f32_16x16x32_bf16(pf, vf, o[nf], 0, 0, 0);
            }
            asm volatile("" ::: "memory");
            __builtin_amdgcn_s_barrier();
            asm volatile("" ::: "memory");
        }

        sum += __shfl_xor(sum, 16, 64);
        sum += __shfl_xor(sum, 32, 64);
        if (quad == 0) sums_l[wave * 16 + l16] = sum;   // wave-local
        float inv_l[4];
#pragma unroll
        for (int r = 0; r < 4; ++r) inv_l[r] = 1.0f / sums_l[wave * 16 + quad * 4 + r];
#pragma unroll
        for (int nf = 0; nf < 4; ++nf)
#pragma unroll
            for (int r = 0; r < 4; ++r) {
                int qr = q0 + quad * 4 + r;
                A[((size_t)(b * S_ + qr)) * HID_ + h * HD_ + nf * 16 + l16] =
                    __float2bfloat16(o[nf][r] * inv_l[r]);
            }
    }
    gbar(bar + 2);

    // ================= phase 3: output projection (512 units) ==============
    if (bid < 512) {
        bf16_t* As = sm;           // 128*32 = 4096 elems (8 KB)
        bf16_t* Bs = sm + 4096;    // 64*32  = 2048 elems (4 KB)
        const int m0 = (bid & 63) * 128, n0 = (bid >> 6) * 64;

        f32x4 acc[2][4] = {};
        for (int k0 = 0; k0 < HID_; k0 += 32) {
#pragma unroll
            for (int rr = 0; rr < 2; ++rr) {
                int slot = rr * 256 + tid;
                int row = slot >> 2;
                int l = (slot & 3) ^ ((row >> 1) & 3);
                glds16(A + (size_t)(m0 + row) * HID_ + k0 + l * 8, As + slot * 8);
            }
            {
                int slot = tid;
                int row = slot >> 2;
                int l = (slot & 3) ^ ((row >> 1) & 3);
                glds16(Wob + (size_t)(n0 + row) * HID_ + k0 + l * 8, Bs + slot * 8);
            }
            __syncthreads();
            bf16x8 af[2], bfr[4];
#pragma unroll
            for (int i = 0; i < 2; ++i) {
                int ra = wave * 32 + i * 16 + l16;
                int pa = quad ^ ((ra >> 1) & 3);
                af[i] = *reinterpret_cast<const bf16x8*>(&As[ra * 32 + pa * 8]);
            }
#pragma unroll
            for (int i = 0; i < 4; ++i) {
                int rb = i * 16 + l16;
                int pb = quad ^ ((rb >> 1) & 3);
                bfr[i] = *reinterpret_cast<const bf16x8*>(&Bs[rb * 32 + pb * 8]);
            }
#pragma unroll
            for (int mi = 0; mi < 2; ++mi)
#pragma unroll
                for (int ni = 0; ni < 4; ++ni)
                    acc[mi][ni] = __builtin_amdgcn_mfma_f32_16x16x32_bf16(af[mi], bfr[ni], acc[mi][ni], 0, 0, 0);
            __syncthreads();
        }
#pragma unroll
        for (int mi = 0; mi < 2; ++mi)
#pragma unroll
            for (int ni = 0; ni < 4; ++ni)
#pragma unroll
                for (int r = 0; r < 4; ++r) {
                    int m = m0 + wave * 32 + mi * 16 + quad * 4 + r;
                    int n = n0 + ni * 16 + l16;
                    out[(size_t)m * HID_ + n] = acc[mi][ni][r];
                }
    }
}

// ---------------------------------------------------------------------------
extern "C" void kernel_launch(void* const* d_in, const int* in_sizes, int n_in,
                              void* d_out, int out_size, void* d_ws, size_t ws_size,
                              hipStream_t stream)
{
    const float* X  = (const float*)d_in[0];
    // d_in[1] = position_ids (broadcast arange(S); pos derived from s index)
    const float* Wq = (const float*)d_in[2];
    const float* Wk = (const float*)d_in[3];
    const float* Wv = (const float*)d_in[4];
    const float* Wo = (const float*)d_in[5];

    char* ws = (char*)d_ws;
    const size_t elems = (size_t)B_ * NH_ * S_ * HD_;   // 4,194,304
    const size_t wsz   = (size_t)HID_ * HID_;           // 262,144
    bf16_t* Q    = (bf16_t*)ws;
    bf16_t* K    = Q + elems;
    bf16_t* Vt   = K + elems;
    bf16_t* Xb   = Vt + elems;          // aliased: A overwrites Xb after qkv
    bf16_t* A    = Xb;
    bf16_t* Wcat = Xb + elems;
    bf16_t* Wob  = Wcat + 3 * wsz;      // total ~35.6 MB
    int*    bar  = (int*)(ws + ((size_t)48 << 20));   // 3 counters, zeroed below

    hipMemsetAsync(bar, 0, 64, stream);
    mega<<<1024, 256, 0, stream>>>(X, Wq, Wk, Wv, Wo,
                                   Xb, Wcat, Wob, Q, K, Vt, A,
                                   (float*)d_out, bar);
}

// Round 11
// 128.702 us; speedup vs baseline: 7.2967x; 7.2967x over previous
//
#include <hip/hip_runtime.h>
#include <hip/hip_bf16.h>
#include <math.h>

// MimiAttention: B=4, S=2048, HID=512, NH=8, HD=64, SW=250, theta=10000
// Round 22: revert megafusion (r21: software global barriers = ~270us each,
// __threadfence L2-writeback storm; GPU idle at 1% util). Back to r20
// 4-kernel structure (125.6us verified) + attn amortization: 128-row
// q-blocks (512 blocks), each wave handles 2 q-tiles (q0A, q0B=q0A+64)
// sharing the staged K/V tiles -> staging traffic and barrier count per
// output halve; K-frag and V-frag LDS reads shared by both q-tiles.
// LDS 26.5KB (2 blocks/CU). cvt/qkv/out = r20 exact.

#define B_   4
#define S_   2048
#define HID_ 512
#define NH_  8
#define HD_  64
#define SW_  250

typedef __bf16 bf16x8 __attribute__((ext_vector_type(8)));
typedef __bf16 bf16x4 __attribute__((ext_vector_type(4)));
typedef float f32x4 __attribute__((ext_vector_type(4)));
using bf16_t = __hip_bfloat16;
typedef unsigned int u32;

// async global->LDS, 16 B per lane (wave-uniform base + lane*16 semantics)
__device__ __forceinline__ void glds16(const void* g, void* l) {
    __builtin_amdgcn_global_load_lds(
        (const __attribute__((address_space(1))) u32*)g,
        (__attribute__((address_space(3))) u32*)l, 16, 0, 0);
}

// ---------------------------------------------------------------------------
// One fused fp32->bf16 convert pass. 2048 elems/block.
// ---------------------------------------------------------------------------
__global__ __launch_bounds__(256) void cvt_all(
    const float* __restrict__ X,  const float* __restrict__ Wq,
    const float* __restrict__ Wk, const float* __restrict__ Wv,
    const float* __restrict__ Wo,
    bf16_t* __restrict__ Xb, bf16_t* __restrict__ Wcat, bf16_t* __restrict__ Wob)
{
    const int blk = blockIdx.x;
    const float* s; bf16_t* d; size_t base;
    if (blk < 2048)      { s = X;  d = Xb;            base = (size_t)blk * 2048; }
    else if (blk < 2176) { s = Wq; d = Wcat;          base = (size_t)(blk - 2048) * 2048; }
    else if (blk < 2304) { s = Wk; d = Wcat + 262144; base = (size_t)(blk - 2176) * 2048; }
    else if (blk < 2432) { s = Wv; d = Wcat + 524288; base = (size_t)(blk - 2304) * 2048; }
    else                 { s = Wo; d = Wob;           base = (size_t)(blk - 2432) * 2048; }
    size_t i = base + (size_t)threadIdx.x * 8;
    float4 a = *reinterpret_cast<const float4*>(s + i);
    float4 b = *reinterpret_cast<const float4*>(s + i + 4);
    bf16x8 r;
    r[0] = (__bf16)a.x; r[1] = (__bf16)a.y; r[2] = (__bf16)a.z; r[3] = (__bf16)a.w;
    r[4] = (__bf16)b.x; r[5] = (__bf16)b.y; r[6] = (__bf16)b.z; r[7] = (__bf16)b.w;
    *reinterpret_cast<bf16x8*>(d + i) = r;
}

// ---------------------------------------------------------------------------
// Fused QKV GEMM (r20 exact): 128x128 tile, BK=32, XOR-swizzled slots,
// RoPE epilogue, V transposed. 768 1-D blocks, XCD-chunked. Double-buffered
// staging, counted vmcnt(4), sched_barrier(0) fences.
// ---------------------------------------------------------------------------
__global__ __launch_bounds__(256) void qkv_gemm(
    const bf16_t* __restrict__ Xb, const bf16_t* __restrict__ Wcat,
    bf16_t* __restrict__ Q, bf16_t* __restrict__ Kbuf, bf16_t* __restrict__ Vt)
{
    __shared__ __align__(16) char smem_raw[34816];  // 32KB dbuf stage / 34KB epi
    bf16_t* const sm = (bf16_t*)smem_raw;
    const int tid = threadIdx.x;
    const int wave = tid >> 6, lane = tid & 63;
    const int quad = lane >> 4, l16 = lane & 15;
    const int wm = wave & 1, wn = wave >> 1;

    const int g = blockIdx.x;
    const int xcd = g & 7, slot = g >> 3;          // slot in [0,96)
    const int mi = xcd * 8 + (slot & 7);           // [0,64)
    const int ni = slot >> 3;                      // [0,12)
    const int m0 = mi * 128, n0 = ni * 128;

    const int srow0 = tid >> 2,           sl0 = (tid & 3) ^ ((srow0 >> 1) & 3);
    const int srow1 = (256 + tid) >> 2,   sl1 = ((256 + tid) & 3) ^ ((srow1 >> 1) & 3);

    glds16(Xb   + (size_t)(m0 + srow0) * HID_ + sl0 * 8, sm + tid * 8);
    glds16(Wcat + (size_t)(n0 + srow0) * HID_ + sl0 * 8, sm + 4096 + tid * 8);
    glds16(Xb   + (size_t)(m0 + srow1) * HID_ + sl1 * 8, sm + (256 + tid) * 8);
    glds16(Wcat + (size_t)(n0 + srow1) * HID_ + sl1 * 8, sm + 4096 + (256 + tid) * 8);

    f32x4 acc[4][4] = {};
    for (int t = 0; t < 16; ++t) {
        const int curo = (t & 1) * 8192;
        if (t + 1 < 16) {
            const int nxto = curo ^ 8192;
            const int k1 = (t + 1) * 32;
            glds16(Xb   + (size_t)(m0 + srow0) * HID_ + k1 + sl0 * 8, sm + nxto + tid * 8);
            glds16(Wcat + (size_t)(n0 + srow0) * HID_ + k1 + sl0 * 8, sm + nxto + 4096 + tid * 8);
            glds16(Xb   + (size_t)(m0 + srow1) * HID_ + k1 + sl1 * 8, sm + nxto + (256 + tid) * 8);
            glds16(Wcat + (size_t)(n0 + srow1) * HID_ + k1 + sl1 * 8, sm + nxto + 4096 + (256 + tid) * 8);
            asm volatile("s_waitcnt vmcnt(4)" ::: "memory");
        } else {
            asm volatile("s_waitcnt vmcnt(0)" ::: "memory");
        }
        __builtin_amdgcn_sched_barrier(0);
        __builtin_amdgcn_s_barrier();
        __builtin_amdgcn_sched_barrier(0);

        bf16x8 af[4], bfr[4];
#pragma unroll
        for (int i = 0; i < 4; ++i) {
            int ra = wm * 64 + i * 16 + l16;
            int rb = wn * 64 + i * 16 + l16;
            int pa = quad ^ ((ra >> 1) & 3);
            int pb = quad ^ ((rb >> 1) & 3);
            af[i]  = *reinterpret_cast<const bf16x8*>(sm + curo + ra * 32 + pa * 8);
            bfr[i] = *reinterpret_cast<const bf16x8*>(sm + curo + 4096 + rb * 32 + pb * 8);
        }
#pragma unroll
        for (int mi2 = 0; mi2 < 4; ++mi2)
#pragma unroll
            for (int ni2 = 0; ni2 < 4; ++ni2)
                acc[mi2][ni2] = __builtin_amdgcn_mfma_f32_16x16x32_bf16(af[mi2], bfr[ni2], acc[mi2][ni2], 0, 0, 0);
        asm volatile("" ::: "memory");
        __builtin_amdgcn_sched_barrier(0);
        __builtin_amdgcn_s_barrier();
        __builtin_amdgcn_sched_barrier(0);
    }

    // ---- epilogue via wave-private 64x68 bf16 LDS tile (4352 elems/wave) ----
    const int seg = n0 >> 9;                      // 0=Q 1=K 2=V
    const int hh = ((n0 & 511) + wn * 64) >> 6;
    bf16_t* wt = sm + wave * 4352;
    const int mbase = m0 + wm * 64;
    const int bb = mbase >> 11;
    const int sbase = mbase & (S_ - 1);

    if (seg < 2) {
        const float qs = (seg == 0) ? 0.125f : 1.0f;
        const float c = 0.41524101186f;           // log2(10000)/32
        float inv0 = exp2f(-(float)l16 * c);
        float inv1 = exp2f(-(float)(l16 + 16) * c);
#pragma unroll
        for (int mi2 = 0; mi2 < 4; ++mi2)
#pragma unroll
            for (int r = 0; r < 4; ++r) {
                int lrow = mi2 * 16 + quad * 4 + r;
                float sf = (float)(sbase + lrow);
#pragma unroll
                for (int ip = 0; ip < 2; ++ip) {
                    float sn, cs_;
                    __sincosf(sf * (ip ? inv1 : inv0), &sn, &cs_);
                    float x1 = acc[mi2][ip][r], x2 = acc[mi2][ip + 2][r];
                    wt[lrow * 68 + ip * 16 + l16]      = __float2bfloat16((x1 * cs_ - x2 * sn) * qs);
                    wt[lrow * 68 + ip * 16 + l16 + 32] = __float2bfloat16((x2 * cs_ + x1 * sn) * qs);
                }
            }
        bf16_t* Y = (seg == 0) ? Q : Kbuf;
#pragma unroll
        for (int it = 0; it < 8; ++it) {
            int e = it * 64 + lane;
            int sr = e >> 3, doff = (e & 7) * 8;
            size_t g2 = ((size_t)(bb * NH_ + hh) * S_ + sbase + sr) * HD_ + doff;
            *reinterpret_cast<bf16x8*>(Y + g2) =
                *reinterpret_cast<const bf16x8*>(wt + sr * 68 + doff);
        }
    } else {
#pragma unroll
        for (int mi2 = 0; mi2 < 4; ++mi2)
#pragma unroll
            for (int ni2 = 0; ni2 < 4; ++ni2)
#pragma unroll
                for (int r = 0; r < 4; ++r)
                    wt[(ni2 * 16 + l16) * 68 + mi2 * 16 + quad * 4 + r] =
                        __float2bfloat16(acc[mi2][ni2][r]);
#pragma unroll
        for (int it = 0; it < 8; ++it) {
            int e = it * 64 + lane;
            int d = e >> 3, soff = (e & 7) * 8;
            size_t g2 = ((size_t)(bb * NH_ + hh) * HD_ + d) * S_ + sbase + soff;
            *reinterpret_cast<bf16x8*>(Vt + g2) =
                *reinterpret_cast<const bf16x8*>(wt + d * 68 + soff);
        }
    }
}

// ---------------------------------------------------------------------------
// Attention: 128-row q-blocks (512 blocks), 4 waves x 2 q-tiles each
// (q0A = q0b + wave*16, q0B = q0A + 64). Block-staged K/V double-buffer
// with counted vmcnt(2); staged tile shared by both q-tiles (k-frags and
// v-frags read once). One-pass no-max softmax. XCD-chunked grid.
// ---------------------------------------------------------------------------
__global__ __launch_bounds__(256) void attn_mfma(
    const bf16_t* __restrict__ Q, const bf16_t* __restrict__ K,
    const bf16_t* __restrict__ Vt, bf16_t* __restrict__ A)
{
    __shared__ __align__(16) __bf16 Ks[2][32 * 64];    // 2 x 4 KB
    __shared__ __align__(16) __bf16 Vs[2][64 * 32];    // 2 x 4 KB
    __shared__ __align__(16) __bf16 pt[4][2][16][40];  // 10 KB
    __shared__ float sums_l[4][2][16];                 // 512 B
    const int tid = threadIdx.x;
    const int wave = tid >> 6, lane = tid & 63;
    const int quad = lane >> 4, l16 = lane & 15;

    // XCD-locality remap (bijective over 512): xcd owns 4 (b,h) pairs
    const int g = blockIdx.x;
    const int xcd = g & 7, slot = g >> 3;          // slot in [0,64)
    const int bh = xcd * 4 + (slot >> 4);          // [0,32)
    const int qt = slot & 15;                      // 128-row q-block
    const int b = bh >> 3, h = bh & 7;
    const int q0b = qt * 128;
    const int q0A = q0b + wave * 16;
    const int q0B = q0A + 64;

    const size_t bh_ = (size_t)(b * NH_ + h) * S_;
    const size_t bhd = (size_t)(b * NH_ + h) * HD_;

    bf16x8 qfA0, qfA1, qfB0, qfB1;
    {
        const bf16_t* qp = Q + (bh_ + q0A + l16) * HD_ + quad * 8;
        qfA0 = *reinterpret_cast<const bf16x8*>(qp);
        qfA1 = *reinterpret_cast<const bf16x8*>(qp + 32);
        const bf16_t* qp2 = Q + (bh_ + q0B + l16) * HD_ + quad * 8;
        qfB0 = *reinterpret_cast<const bf16x8*>(qp2);
        qfB1 = *reinterpret_cast<const bf16x8*>(qp2 + 32);
    }
    const int kstartB = (q0b > SW_) ? ((q0b - SW_) & ~31) : 0;
    const int ntB = (q0b + 159 - kstartB) >> 5;    // 4, 8, or 12; block-uniform
    const int qqA = q0A + l16, qqB = q0B + l16;

    const int krow = tid >> 3, kl = (tid & 7) ^ (krow & 7);   // K stage addr
    const int vrow = tid >> 2, vl = (tid & 3) ^ (vrow & 3);   // V stage addr

    {
        const int kb = kstartB;
        glds16(K  + (bh_ + kb + krow) * HD_ + kl * 8, &Ks[0][tid * 8]);
        glds16(Vt + (bhd + vrow) * S_ + kb + vl * 8, &Vs[0][tid * 8]);
    }

    float sumA = 0.f, sumB = 0.f;
    f32x4 oA[4] = {}, oB[4] = {};
    for (int t = 0; t < ntB; ++t) {
        const int cur = t & 1;
        const int kb = kstartB + t * 32;
        if (t + 1 < ntB) {
            const int kb2 = kb + 32;
            glds16(K  + (bh_ + kb2 + krow) * HD_ + kl * 8, &Ks[cur ^ 1][tid * 8]);
            glds16(Vt + (bhd + vrow) * S_ + kb2 + vl * 8, &Vs[cur ^ 1][tid * 8]);
            asm volatile("s_waitcnt vmcnt(2)" ::: "memory");
        } else {
            asm volatile("s_waitcnt vmcnt(0)" ::: "memory");
        }
        __builtin_amdgcn_s_barrier();
        asm volatile("" ::: "memory");

        // ---- QK^T for both q-tiles, sharing K-frag LDS reads ----
#pragma unroll
        for (int half = 0; half < 2; ++half) {
            const int rowt = half * 16 + l16;
            const int p0 = quad ^ (rowt & 7);
            const int p1 = (quad ^ 4) ^ (rowt & 7);
            bf16x8 k0 = *reinterpret_cast<const bf16x8*>(&Ks[cur][rowt * 64 + p0 * 8]);
            bf16x8 k1 = *reinterpret_cast<const bf16x8*>(&Ks[cur][rowt * 64 + p1 * 8]);
            f32x4 zA = {}, zB = {};
            zA = __builtin_amdgcn_mfma_f32_16x16x32_bf16(k0, qfA0, zA, 0, 0, 0);
            zA = __builtin_amdgcn_mfma_f32_16x16x32_bf16(k1, qfA1, zA, 0, 0, 0);
            zB = __builtin_amdgcn_mfma_f32_16x16x32_bf16(k0, qfB0, zB, 0, 0, 0);
            zB = __builtin_amdgcn_mfma_f32_16x16x32_bf16(k1, qfB1, zB, 0, 0, 0);
            const int kbase = kb + half * 16 + quad * 4;
            bf16x4 pkA, pkB;
#pragma unroll
            for (int r = 0; r < 4; ++r) {
                int key = kbase + r;
                bool keepA = (key <= qqA) && (qqA - key <= SW_);
                bool keepB = (key <= qqB) && (qqB - key <= SW_);
                float pA = keepA ? __expf(zA[r]) : 0.f;
                float pB = keepB ? __expf(zB[r]) : 0.f;
                sumA += pA; sumB += pB;
                pkA[r] = (__bf16)pA; pkB[r] = (__bf16)pB;
            }
            *reinterpret_cast<bf16x4*>(&pt[wave][0][l16][half * 16 + quad * 4]) = pkA;
            *reinterpret_cast<bf16x4*>(&pt[wave][1][l16][half * 16 + quad * 4]) = pkB;
        }
        // ---- PV for both q-tiles, sharing V-frag LDS reads ----
        bf16x8 pfA = *reinterpret_cast<const bf16x8*>(&pt[wave][0][l16][quad * 8]);
        bf16x8 pfB = *reinterpret_cast<const bf16x8*>(&pt[wave][1][l16][quad * 8]);
#pragma unroll
        for (int nf = 0; nf < 4; ++nf) {
            const int rowv = nf * 16 + l16;
            const int pv = quad ^ (rowv & 3);
            bf16x8 vf = *reinterpret_cast<const bf16x8*>(&Vs[cur][rowv * 32 + pv * 8]);
            oA[nf] = __builtin_amdgcn_mfma_f32_16x16x32_bf16(pfA, vf, oA[nf], 0, 0, 0);
            oB[nf] = __builtin_amdgcn_mfma_f32_16x16x32_bf16(pfB, vf, oB[nf], 0, 0, 0);
        }
        asm volatile("" ::: "memory");
        __builtin_amdgcn_s_barrier();
        asm volatile("" ::: "memory");
    }

    sumA += __shfl_xor(sumA, 16, 64);
    sumA += __shfl_xor(sumA, 32, 64);
    sumB += __shfl_xor(sumB, 16, 64);
    sumB += __shfl_xor(sumB, 32, 64);
    if (quad == 0) { sums_l[wave][0][l16] = sumA; sums_l[wave][1][l16] = sumB; }
    float invA[4], invB[4];
#pragma unroll
    for (int r = 0; r < 4; ++r) {
        invA[r] = 1.0f / sums_l[wave][0][quad * 4 + r];
        invB[r] = 1.0f / sums_l[wave][1][quad * 4 + r];
    }
#pragma unroll
    for (int nf = 0; nf < 4; ++nf)
#pragma unroll
        for (int r = 0; r < 4; ++r) {
            int qrA = q0A + quad * 4 + r;
            int qrB = q0B + quad * 4 + r;
            A[((size_t)(b * S_ + qrA)) * HID_ + h * HD_ + nf * 16 + l16] =
                __float2bfloat16(oA[nf][r] * invA[r]);
            A[((size_t)(b * S_ + qrB)) * HID_ + h * HD_ + nf * 16 + l16] =
                __float2bfloat16(oB[nf][r] * invB[r]);
        }
}

// ---------------------------------------------------------------------------
// Output projection (r20 exact): 128x64 tile, BK=32, single-buffer
// __syncthreads K-loop, direct fp32 stores.
// ---------------------------------------------------------------------------
__global__ __launch_bounds__(256) void out_proj(
    const bf16_t* __restrict__ Ain, const bf16_t* __restrict__ Wob,
    float* __restrict__ out)
{
    __shared__ __align__(16) bf16_t As[128 * 32];  // 8 KB
    __shared__ __align__(16) bf16_t Bs[64 * 32];   // 4 KB
    const int tid = threadIdx.x;
    const int wave = tid >> 6, lane = tid & 63;
    const int quad = lane >> 4, l16 = lane & 15;
    const int m0 = blockIdx.x * 128, n0 = blockIdx.y * 64;

    f32x4 acc[2][4] = {};
    for (int k0 = 0; k0 < HID_; k0 += 32) {
#pragma unroll
        for (int rr = 0; rr < 2; ++rr) {
            int slot = rr * 256 + tid;
            int row = slot >> 2;
            int l = (slot & 3) ^ ((row >> 1) & 3);
            glds16(Ain + (size_t)(m0 + row) * HID_ + k0 + l * 8, As + slot * 8);
        }
        {
            int slot = tid;                        // 256 slots: one round
            int row = slot >> 2;
            int l = (slot & 3) ^ ((row >> 1) & 3);
            glds16(Wob + (size_t)(n0 + row) * HID_ + k0 + l * 8, Bs + slot * 8);
        }
        __syncthreads();
        bf16x8 af[2], bfr[4];
#pragma unroll
        for (int i = 0; i < 2; ++i) {
            int ra = wave * 32 + i * 16 + l16;
            int pa = quad ^ ((ra >> 1) & 3);
            af[i] = *reinterpret_cast<const bf16x8*>(&As[ra * 32 + pa * 8]);
        }
#pragma unroll
        for (int i = 0; i < 4; ++i) {
            int rb = i * 16 + l16;
            int pb = quad ^ ((rb >> 1) & 3);
            bfr[i] = *reinterpret_cast<const bf16x8*>(&Bs[rb * 32 + pb * 8]);
        }
#pragma unroll
        for (int mi = 0; mi < 2; ++mi)
#pragma unroll
            for (int ni = 0; ni < 4; ++ni)
                acc[mi][ni] = __builtin_amdgcn_mfma_f32_16x16x32_bf16(af[mi], bfr[ni], acc[mi][ni], 0, 0, 0);
        __syncthreads();
    }
#pragma unroll
    for (int mi = 0; mi < 2; ++mi)
#pragma unroll
        for (int ni = 0; ni < 4; ++ni)
#pragma unroll
            for (int r = 0; r < 4; ++r) {
                int m = m0 + wave * 32 + mi * 16 + quad * 4 + r;
                int n = n0 + ni * 16 + l16;
                out[(size_t)m * HID_ + n] = acc[mi][ni][r];
            }
}

// ---------------------------------------------------------------------------
extern "C" void kernel_launch(void* const* d_in, const int* in_sizes, int n_in,
                              void* d_out, int out_size, void* d_ws, size_t ws_size,
                              hipStream_t stream)
{
    const float* X  = (const float*)d_in[0];
    // d_in[1] = position_ids (broadcast arange(S); pos derived from s index)
    const float* Wq = (const float*)d_in[2];
    const float* Wk = (const float*)d_in[3];
    const float* Wv = (const float*)d_in[4];
    const float* Wo = (const float*)d_in[5];

    char* ws = (char*)d_ws;
    const size_t elems = (size_t)B_ * NH_ * S_ * HD_;   // 4,194,304
    const size_t wsz   = (size_t)HID_ * HID_;           // 262,144
    bf16_t* Q    = (bf16_t*)ws;
    bf16_t* K    = Q + elems;
    bf16_t* Vt   = K + elems;
    bf16_t* Xb   = Vt + elems;          // aliased: A overwrites Xb after qkv
    bf16_t* A    = Xb;
    bf16_t* Wcat = Xb + elems;
    bf16_t* Wob  = Wcat + 3 * wsz;      // total ~35.6 MB

    cvt_all<<<2560, 256, 0, stream>>>(X, Wq, Wk, Wv, Wo, Xb, Wcat, Wob);
    qkv_gemm<<<768, 256, 0, stream>>>(Xb, Wcat, Q, K, Vt);
    attn_mfma<<<512, 256, 0, stream>>>(Q, K, Vt, A);
    out_proj<<<dim3(64, 8), 256, 0, stream>>>(A, Wob, (float*)d_out);
}